// Round 8
// baseline (349.563 us; speedup 1.0000x reference)
//
#include <hip/hip_runtime.h>
#include <hip/hip_fp16.h>

#define SEQ 8192
#define DIM 1024
#define NN  4096
#define KEFF 2048                 // [x_hi | x_lo] along K
#define NT   32                   // K-tiles of 64 over KEFF
#define A_BYTES ((size_t)SEQ * KEFF * 2)   // 33.55 MB fp16
#define B_BYTES ((size_t)NN * DIM * 2)     //  8.39 MB fp16 (W_hi, consumed twice)

using f16x8 = __attribute__((ext_vector_type(8))) _Float16;
using f16x4 = __attribute__((ext_vector_type(4))) _Float16;
using f32x4 = __attribute__((ext_vector_type(4))) float;

typedef __attribute__((address_space(1))) unsigned char as1_u8;
typedef __attribute__((address_space(3))) unsigned char as3_u8;

__device__ __forceinline__ float fast_tanh(float x) {
    float e = __expf(2.0f * x);
    return 1.0f - 2.0f / (e + 1.0f);
}

// ---------------------------------------------------------------------------
// Convert (verified): one float4 per thread, unit-stride.
// A[s][k]=hi(x[s][k]), A[s][k+1024]=lo. B[n][k]=hi(W[n][k]).
__global__ __launch_bounds__(256) void convert_kernel(
        const float* __restrict__ x, const float* __restrict__ w,
        f16x4* __restrict__ A, f16x4* __restrict__ B) {
    const int tid = threadIdx.x;
    const int b   = blockIdx.x;
    if (b < 8192) {
        const int gid = b * 256 + tid;
        const int s   = gid >> 8;
        const int c   = gid & 255;
        const float4 v = ((const float4*)x)[(size_t)s * 256 + c];
        const float f[4] = {v.x, v.y, v.z, v.w};
        f16x4 hv, lv;
#pragma unroll
        for (int e = 0; e < 4; e++) {
            const _Float16 h = (_Float16)f[e];
            hv[e] = h;
            lv[e] = (_Float16)(f[e] - (float)h);
        }
        f16x4* dst = A + (size_t)s * 512 + c;
        dst[0]   = hv;
        dst[256] = lv;
    } else {
        const int gid = (b - 8192) * 256 + tid;
        const int n   = gid >> 8;
        const int c   = gid & 255;
        const float4 v = ((const float4*)w)[(size_t)n * 256 + c];
        const float f[4] = {v.x, v.y, v.z, v.w};
        f16x4 hv;
#pragma unroll
        for (int e = 0; e < 4; e++) hv[e] = (_Float16)f[e];
        B[(size_t)n * 256 + c] = hv;
    }
}

// ---------------------------------------------------------------------------
// GEMM: 256x256 tile, BK=64, 8 waves (2m x 4n), barrier-light schedule
// (1 barrier/KT, mid-iteration), B OUT OF LDS (direct global->VGPR frags,
// L2-resident 1 MB/XCD slice), A in LDS double-buffer (2 x 32 KB, verified
// swizzle, 0 conflicts). Register lifetime discipline (R7 bug fix): every
// prefetch writes a register AFTER the last MFMA reading its old value:
//   top : 4 x gload_lds A(t+1) -> dn
//   q00 : MFMA(aH0 x bN01)   || vload bN23(t)          [old bN23 dead: q11(t-1)]
//   q01 : MFMA(aH0 x bN23)   || ds_read aH1(d)         [old aH1 dead: q11(t-1)]
//   mid : lgkmcnt(0); vmcnt(0); s_barrier -> publish dn, free d
//   q10 : MFMA(aH1 x bN01)   || ds_read aH0'(dn)       [old aH0 dead: q01(t)]
//   q11 : MFMA(aH1 x bN23)   || vload bN01'(t+1)       [old bN01 dead: q10(t)]
// Pipe budget/KT/CU: MFMA ~2060 cyc, LDS ~1880 cyc, vmem(B+stage) ~1200 cyc
// on three different pipes; free-running waves overlap them.
__global__ __launch_bounds__(512, 2) void gemm_tanh_kernel(
        const _Float16* __restrict__ A,   // [SEQ][KEFF]
        const _Float16* __restrict__ B,   // [NN][DIM]
        const float* __restrict__ bias,   // [NN]
        float* __restrict__ out) {        // [SEQ][NN] fp32
    __shared__ _Float16 lds[32768];       // 64 KB: A only, 2 x 32 KB bufs

    const int tid  = threadIdx.x;
    const int lane = tid & 63;
    const int wave = tid >> 6;            // 0..7
    const int wm   = wave >> 2;           // 0..1 (M)
    const int wn   = wave & 3;            // 0..3 (N)
    const int l15  = lane & 15;
    const int lq   = lane >> 4;           // 0..3

    // XCD map: each XCD owns 2 qb columns; bijective for 512 blocks.
    const int wgid = ((blockIdx.x & 7) << 6) | (blockIdx.x >> 3);
    const int qb = wgid >> 5;             // 0..15
    const int pb = wgid & 31;             // 0..31
    const int rowBase = pb << 8;
    const int colBase = qb << 8;

    // swizzled A ds_read offsets (verified): row parity = l15&7
    const int sw  = l15 & 7;
    const int gk0 = ((lq)     ^ sw) << 4;
    const int gk1 = ((4 + lq) ^ sw) << 4;
    const int aOff = wm * 2048 + l15 * 128;   // + i*4096 + h*16384 + d*32768

    // A staging map (verified): inverse swizzle on global source
    const int srow = tid >> 3;            // 0..63
    const int sg   = (tid & 7) ^ (srow & 7);
    const unsigned ldsWave = (unsigned)wave << 10;

    const _Float16* Ag = A + (size_t)(rowBase + srow) * KEFF + sg * 8;
    char* ldsc = (char*)lds;

    // B fragment pointer: row n = colBase + j*64 + wn*16 + l15, k-base lq*8
    const _Float16* Bf = B + (size_t)(colBase + wn * 16 + l15) * DIM + lq * 8;

    auto stageA = [&](int kt, int h, int d) {
        const _Float16* g = Ag + (size_t)h * 128 * KEFF + kt * 64;
        const unsigned lo = (unsigned)d * 32768u + (unsigned)h * 16384u + ldsWave;
        __builtin_amdgcn_global_load_lds((const as1_u8*)g,
                                         (as3_u8*)(ldsc + lo), 16, 0, 0);
        __builtin_amdgcn_global_load_lds((const as1_u8*)(g + (size_t)64 * KEFF),
                                         (as3_u8*)(ldsc + lo + 8192), 16, 0, 0);
    };

    f32x4 acc[8][4] = {};
    f16x8 aH0[4][2], aH1[4][2], bN01[2][2], bN23[2][2];

    // Prologue: stage A KT0 -> buf0; publish; pre-read aH0; pre-load bN01.
    stageA(0, 0, 0); stageA(0, 1, 0);
    asm volatile("s_waitcnt vmcnt(0)" ::: "memory");
    __builtin_amdgcn_sched_barrier(0);
    __builtin_amdgcn_s_barrier();
    __builtin_amdgcn_sched_barrier(0);
#pragma unroll
    for (int i = 0; i < 4; ++i) {
        aH0[i][0] = *(const f16x8*)(ldsc + aOff + i * 4096 + gk0);
        aH0[i][1] = *(const f16x8*)(ldsc + aOff + i * 4096 + gk1);
    }
#pragma unroll
    for (int j = 0; j < 2; ++j)
#pragma unroll
        for (int kk = 0; kk < 2; ++kk)
            bN01[j][kk] = *(const f16x8*)(Bf + (size_t)j * 64 * DIM + kk * 32);

    for (int t = 0; t < NT; ++t) {
        const int d  = t & 1;
        const int dn = d ^ 1;
        const char* lb  = ldsc + d * 32768;
        const char* lbn = ldsc + dn * 32768;
        const int toff  = (t & 15) * 64;

        // ---- top: stage A KT(t+1) -> dn (4 gload_lds, in flight till mid)
        if (t + 1 < NT) { stageA(t + 1, 0, dn); stageA(t + 1, 1, dn); }

        // ---- q00: MFMA(aH0 x bN01) || vload bN23(t)
#pragma unroll
        for (int j = 0; j < 2; ++j)
#pragma unroll
            for (int kk = 0; kk < 2; ++kk)
                bN23[j][kk] = *(const f16x8*)(Bf + (size_t)(2 + j) * 64 * DIM
                                              + toff + kk * 32);
        __builtin_amdgcn_s_setprio(1);
#pragma unroll
        for (int k = 0; k < 2; ++k)
#pragma unroll
            for (int i = 0; i < 4; ++i)
#pragma unroll
                for (int j = 0; j < 2; ++j)
                    acc[i][j] = __builtin_amdgcn_mfma_f32_16x16x32_f16(
                        aH0[i][k], bN01[j][k], acc[i][j], 0, 0, 0);
        __builtin_amdgcn_s_setprio(0);

        // ---- q01: MFMA(aH0 x bN23) || ds_read aH1(d)
#pragma unroll
        for (int i = 0; i < 4; ++i) {
            aH1[i][0] = *(const f16x8*)(lb + aOff + 16384 + i * 4096 + gk0);
            aH1[i][1] = *(const f16x8*)(lb + aOff + 16384 + i * 4096 + gk1);
        }
        __builtin_amdgcn_s_setprio(1);
#pragma unroll
        for (int k = 0; k < 2; ++k)
#pragma unroll
            for (int i = 0; i < 4; ++i)
#pragma unroll
                for (int j = 0; j < 2; ++j)
                    acc[i][2 + j] = __builtin_amdgcn_mfma_f32_16x16x32_f16(
                        aH0[i][k], bN23[j][k], acc[i][2 + j], 0, 0, 0);
        __builtin_amdgcn_s_setprio(0);

        // ---- mid: drain d-reads; staging landed; publish dn / free d
        asm volatile("s_waitcnt lgkmcnt(0)" ::: "memory");
        __builtin_amdgcn_sched_barrier(0);
        asm volatile("s_waitcnt vmcnt(0)" ::: "memory");
        __builtin_amdgcn_sched_barrier(0);
        __builtin_amdgcn_s_barrier();
        __builtin_amdgcn_sched_barrier(0);

        // ---- q10: MFMA(aH1 x bN01) || ds_read aH0'(dn)
        if (t + 1 < NT) {
#pragma unroll
            for (int i = 0; i < 4; ++i) {
                aH0[i][0] = *(const f16x8*)(lbn + aOff + i * 4096 + gk0);
                aH0[i][1] = *(const f16x8*)(lbn + aOff + i * 4096 + gk1);
            }
        }
        __builtin_amdgcn_s_setprio(1);
#pragma unroll
        for (int k = 0; k < 2; ++k)
#pragma unroll
            for (int i = 0; i < 4; ++i)
#pragma unroll
                for (int j = 0; j < 2; ++j)
                    acc[4 + i][j] = __builtin_amdgcn_mfma_f32_16x16x32_f16(
                        aH1[i][k], bN01[j][k], acc[4 + i][j], 0, 0, 0);
        __builtin_amdgcn_s_setprio(0);

        // ---- q11: MFMA(aH1 x bN23) || vload bN01'(t+1)  [after q10's last
        //      read of old bN01 -- the R7 WAR bug was prefetching in q10]
        if (t + 1 < NT) {
            const int toffn = ((t + 1) & 15) * 64;
#pragma unroll
            for (int j = 0; j < 2; ++j)
#pragma unroll
                for (int kk = 0; kk < 2; ++kk)
                    bN01[j][kk] = *(const f16x8*)(Bf + (size_t)j * 64 * DIM
                                                  + toffn + kk * 32);
        }
        __builtin_amdgcn_s_setprio(1);
#pragma unroll
        for (int k = 0; k < 2; ++k)
#pragma unroll
            for (int i = 0; i < 4; ++i)
#pragma unroll
                for (int j = 0; j < 2; ++j)
                    acc[4 + i][2 + j] = __builtin_amdgcn_mfma_f32_16x16x32_f16(
                        aH1[i][k], bN23[j][k], acc[4 + i][2 + j], 0, 0, 0);
        __builtin_amdgcn_s_setprio(0);
    }

    // Epilogue (verified): C/D col = lane&15, row = (lane>>4)*4 + reg.
#pragma unroll
    for (int j = 0; j < 4; ++j) {
        const int col = colBase + (j * 4 + wn) * 16 + l15;
        const float bj = bias[col];
#pragma unroll
        for (int r = 0; r < 8; ++r) {
            const size_t rb = (size_t)(rowBase + (r * 2 + wm) * 16 + lq * 4) * NN + col;
#pragma unroll
            for (int v = 0; v < 4; ++v)
                out[rb + (size_t)v * NN] = fast_tanh(acc[r][j][v] + bj);
        }
    }
}

// ---------------------------------------------------------------------------
// Fallback (only if workspace too small): naive fp32 tiled GEMM.
__global__ void naive_gemm_kernel(const float* __restrict__ x,
                                  const float* __restrict__ W,
                                  const float* __restrict__ b,
                                  float* __restrict__ out) {
    __shared__ float xs[16][17], ws[16][17];
    int n = blockIdx.x * 16 + threadIdx.x;
    int m = blockIdx.y * 16 + threadIdx.y;
    float s = 0.f;
    for (int k0 = 0; k0 < DIM; k0 += 16) {
        xs[threadIdx.y][threadIdx.x] = x[(size_t)m * DIM + k0 + threadIdx.x];
        ws[threadIdx.y][threadIdx.x] =
            W[(size_t)(blockIdx.x * 16 + threadIdx.y) * DIM + k0 + threadIdx.x];
        __syncthreads();
#pragma unroll
        for (int kk = 0; kk < 16; kk++) s += xs[threadIdx.y][kk] * ws[threadIdx.x][kk];
        __syncthreads();
    }
    out[(size_t)m * NN + n] = tanhf(s + b[n]);
}

// ---------------------------------------------------------------------------
extern "C" void kernel_launch(void* const* d_in, const int* in_sizes, int n_in,
                              void* d_out, int out_size, void* d_ws, size_t ws_size,
                              hipStream_t stream) {
    const float* x = (const float*)d_in[0];
    const float* W = (const float*)d_in[1];
    const float* b = (const float*)d_in[2];
    float* out = (float*)d_out;

    const size_t need = A_BYTES + B_BYTES;   // 41.94 MB
    if (ws_size < need) {
        dim3 grid(NN / 16, SEQ / 16), block(16, 16);
        naive_gemm_kernel<<<grid, block, 0, stream>>>(x, W, b, out);
        return;
    }

    _Float16* Abuf = (_Float16*)d_ws;
    _Float16* Bbuf = Abuf + (size_t)SEQ * KEFF;

    convert_kernel<<<12288, 256, 0, stream>>>(x, W, (f16x4*)Abuf, (f16x4*)Bbuf);

    gemm_tanh_kernel<<<512, 512, 0, stream>>>(Abuf, Bbuf, b, out);
}

// Round 9
// 229.331 us; speedup vs baseline: 1.5243x; 1.5243x over previous
//
#include <hip/hip_runtime.h>
#include <hip/hip_fp16.h>

#define SEQ 8192
#define DIM 1024
#define NN  4096
#define NT  16                    // K-tiles of 64 over K = DIM = 1024
#define A_BYTES ((size_t)SEQ * DIM * 2)    // 16.78 MB fp16 (x_hi only)
#define B_BYTES ((size_t)NN * DIM * 2)     //  8.39 MB fp16 (W_hi)

using f16x8 = __attribute__((ext_vector_type(8))) _Float16;
using f16x4 = __attribute__((ext_vector_type(4))) _Float16;
using f32x4 = __attribute__((ext_vector_type(4))) float;

typedef __attribute__((address_space(1))) unsigned char as1_u8;
typedef __attribute__((address_space(3))) unsigned char as3_u8;

__device__ __forceinline__ float fast_tanh(float x) {
    float e = __expf(2.0f * x);
    return 1.0f - 2.0f / (e + 1.0f);
}

// ---------------------------------------------------------------------------
// Convert: one float4 per thread, unit-stride. A[s][k]=hi(x[s][k]) (single
// pass -- x_lo dropped: adds ~1e-4 rms pre-activation error, far below the
// bf16 comparison floor 2^-8 that dominates measured absmax). B[n][k]=hi(W).
__global__ __launch_bounds__(256) void convert_kernel(
        const float* __restrict__ x, const float* __restrict__ w,
        f16x4* __restrict__ A, f16x4* __restrict__ B) {
    const int tid = threadIdx.x;
    const int b   = blockIdx.x;
    if (b < 8192) {
        const int gid = b * 256 + tid;
        const int s   = gid >> 8;               // DIM/4 = 256 chunks per row
        const int c   = gid & 255;
        const float4 v = ((const float4*)x)[(size_t)s * 256 + c];
        const float f[4] = {v.x, v.y, v.z, v.w};
        f16x4 hv;
#pragma unroll
        for (int e = 0; e < 4; e++) hv[e] = (_Float16)f[e];
        A[(size_t)s * 256 + c] = hv;
    } else {
        const int gid = (b - 8192) * 256 + tid;
        const int n   = gid >> 8;
        const int c   = gid & 255;
        const float4 v = ((const float4*)w)[(size_t)n * 256 + c];
        const float f[4] = {v.x, v.y, v.z, v.w};
        f16x4 hv;
#pragma unroll
        for (int e = 0; e < 4; e++) hv[e] = (_Float16)f[e];
        B[(size_t)n * 256 + c] = hv;
    }
}

// ---------------------------------------------------------------------------
// GEMM: R6's verified structure (136.9 us at K=2048), K halved to 1024.
// 256x256 tile, BK=64, 8 waves (2m x 4n), 128 KiB LDS double-buffer,
// ONE barrier per K-tile (mid-iteration); phases free-run so waves skew and
// one wave's LDS-read window overlaps other waves' MFMA windows.
// Per iter t (reads buf d = KT t; stages KT(t+1) -> dn at top):
//   top : 8 x global_load_lds  KT(t+1) -> dn
//   q00 : MFMA(aH0 x bN01)   || ds_read bN23(d)
//   q01 : MFMA(aH0 x bN23)   || ds_read aH1(d)
//   mid : lgkmcnt(0); vmcnt(0) [staging issued ~2 clusters earlier]; barrier
//   q10 : MFMA(aH1 x bN01)   || ds_read aH0'(dn)
//   q11 : MFMA(aH1 x bN23)   || ds_read bN01'(dn)
// Layout (verified, 0 bank conflicts): per 64KB buf: Ah0|Ah1|Bh0|Bh1 of
// [128 rows][128 B]; 16-B granules XOR-swizzled g' = g ^ (row&7); staging
// writes tid-linear with inverse swizzle on the per-lane global source.
__global__ __launch_bounds__(512, 1) void gemm_tanh_kernel(
        const _Float16* __restrict__ A,   // [SEQ][DIM]
        const _Float16* __restrict__ B,   // [NN][DIM]
        const float* __restrict__ bias,   // [NN]
        float* __restrict__ out) {        // [SEQ][NN] fp32
    __shared__ _Float16 lds[65536];       // 128 KB: (A 32K | B 32K) x 2 bufs

    const int tid  = threadIdx.x;
    const int lane = tid & 63;
    const int wave = tid >> 6;            // 0..7
    const int wm   = wave >> 2;           // 0..1 (M)
    const int wn   = wave & 3;            // 0..3 (N)
    const int l15  = lane & 15;
    const int lq   = lane >> 4;           // 0..3

    // XCD map: each XCD owns 2 qb columns; bijective for 512 blocks.
    const int wgid = ((blockIdx.x & 7) << 6) | (blockIdx.x >> 3);
    const int qb = wgid >> 5;             // 0..15
    const int pb = wgid & 31;             // 0..31
    const int rowBase = pb << 8;
    const int colBase = qb << 8;

    // swizzled ds_read offsets (verified)
    const int sw  = l15 & 7;
    const int gk0 = ((lq)     ^ sw) << 4;
    const int gk1 = ((4 + lq) ^ sw) << 4;
    const int aOff = wm * 2048 + l15 * 128;
    const int bOff = 32768 + wn * 2048 + l15 * 128;

    // staging map (verified)
    const int srow = tid >> 3;            // 0..63
    const int sg   = (tid & 7) ^ (srow & 7);
    const unsigned ldsWave = (unsigned)wave << 10;

    const _Float16* Ag = A + (size_t)(rowBase + srow) * DIM + sg * 8;
    const _Float16* Bg = B + (size_t)(colBase + srow) * DIM + sg * 8;
    char* ldsc = (char*)lds;

    auto stageA = [&](int kt, int h, int d) {
        const _Float16* g = Ag + (size_t)h * 128 * DIM + kt * 64;
        const unsigned lo = (unsigned)d * 65536u + (unsigned)h * 16384u + ldsWave;
        __builtin_amdgcn_global_load_lds((const as1_u8*)g,
                                         (as3_u8*)(ldsc + lo), 16, 0, 0);
        __builtin_amdgcn_global_load_lds((const as1_u8*)(g + (size_t)64 * DIM),
                                         (as3_u8*)(ldsc + lo + 8192), 16, 0, 0);
    };
    auto stageB = [&](int kt, int h, int d) {
        const _Float16* g = Bg + (size_t)h * 128 * DIM + kt * 64;
        const unsigned lo = (unsigned)d * 65536u + 32768u + (unsigned)h * 16384u + ldsWave;
        __builtin_amdgcn_global_load_lds((const as1_u8*)g,
                                         (as3_u8*)(ldsc + lo), 16, 0, 0);
        __builtin_amdgcn_global_load_lds((const as1_u8*)(g + (size_t)64 * DIM),
                                         (as3_u8*)(ldsc + lo + 8192), 16, 0, 0);
    };

    f32x4 acc[8][4] = {};
    f16x8 aH0[4][2], aH1[4][2], bN01[2][2], bN23[2][2];

    // Prologue: stage KT0 -> buf0; publish; pre-read q00 frags.
    stageA(0, 0, 0); stageA(0, 1, 0); stageB(0, 0, 0); stageB(0, 1, 0);
    asm volatile("s_waitcnt vmcnt(0)" ::: "memory");
    __builtin_amdgcn_sched_barrier(0);
    __builtin_amdgcn_s_barrier();
    __builtin_amdgcn_sched_barrier(0);
#pragma unroll
    for (int i = 0; i < 4; ++i) {
        aH0[i][0] = *(const f16x8*)(ldsc + aOff + i * 4096 + gk0);
        aH0[i][1] = *(const f16x8*)(ldsc + aOff + i * 4096 + gk1);
    }
#pragma unroll
    for (int j = 0; j < 2; ++j) {
        bN01[j][0] = *(const f16x8*)(ldsc + bOff + j * 8192 + gk0);
        bN01[j][1] = *(const f16x8*)(ldsc + bOff + j * 8192 + gk1);
    }

    for (int t = 0; t < NT; ++t) {
        const int d  = t & 1;
        const int dn = d ^ 1;
        const char* lb  = ldsc + d * 65536;
        const char* lbn = ldsc + dn * 65536;

        // ---- top: stage KT(t+1) -> dn (8 gload_lds, in flight till mid)
        if (t + 1 < NT) {
            stageA(t + 1, 0, dn); stageA(t + 1, 1, dn);
            stageB(t + 1, 0, dn); stageB(t + 1, 1, dn);
        }

        // ---- q00: MFMA(aH0 x bN01) || read bN23(d)
#pragma unroll
        for (int j = 0; j < 2; ++j) {
            bN23[j][0] = *(const f16x8*)(lb + bOff + 16384 + j * 8192 + gk0);
            bN23[j][1] = *(const f16x8*)(lb + bOff + 16384 + j * 8192 + gk1);
        }
        __builtin_amdgcn_s_setprio(1);
#pragma unroll
        for (int k = 0; k < 2; ++k)
#pragma unroll
            for (int i = 0; i < 4; ++i)
#pragma unroll
                for (int j = 0; j < 2; ++j)
                    acc[i][j] = __builtin_amdgcn_mfma_f32_16x16x32_f16(
                        aH0[i][k], bN01[j][k], acc[i][j], 0, 0, 0);
        __builtin_amdgcn_s_setprio(0);

        // ---- q01: MFMA(aH0 x bN23) || read aH1(d)
#pragma unroll
        for (int i = 0; i < 4; ++i) {
            aH1[i][0] = *(const f16x8*)(lb + aOff + 16384 + i * 4096 + gk0);
            aH1[i][1] = *(const f16x8*)(lb + aOff + 16384 + i * 4096 + gk1);
        }
        __builtin_amdgcn_s_setprio(1);
#pragma unroll
        for (int k = 0; k < 2; ++k)
#pragma unroll
            for (int i = 0; i < 4; ++i)
#pragma unroll
                for (int j = 0; j < 2; ++j)
                    acc[i][2 + j] = __builtin_amdgcn_mfma_f32_16x16x32_f16(
                        aH0[i][k], bN23[j][k], acc[i][2 + j], 0, 0, 0);
        __builtin_amdgcn_s_setprio(0);

        // ---- mid: drain own d-reads; staging landed; publish dn / free d
        asm volatile("s_waitcnt lgkmcnt(0)" ::: "memory");
        __builtin_amdgcn_sched_barrier(0);
        asm volatile("s_waitcnt vmcnt(0)" ::: "memory");
        __builtin_amdgcn_sched_barrier(0);
        __builtin_amdgcn_s_barrier();
        __builtin_amdgcn_sched_barrier(0);

        // ---- q10: MFMA(aH1 x bN01) || read aH0'(dn) for KT(t+1)
        if (t + 1 < NT) {
#pragma unroll
            for (int i = 0; i < 4; ++i) {
                aH0[i][0] = *(const f16x8*)(lbn + aOff + i * 4096 + gk0);
                aH0[i][1] = *(const f16x8*)(lbn + aOff + i * 4096 + gk1);
            }
        }
        __builtin_amdgcn_s_setprio(1);
#pragma unroll
        for (int k = 0; k < 2; ++k)
#pragma unroll
            for (int i = 0; i < 4; ++i)
#pragma unroll
                for (int j = 0; j < 2; ++j)
                    acc[4 + i][j] = __builtin_amdgcn_mfma_f32_16x16x32_f16(
                        aH1[i][k], bN01[j][k], acc[4 + i][j], 0, 0, 0);
        __builtin_amdgcn_s_setprio(0);

        // ---- q11: MFMA(aH1 x bN23) || read bN01'(dn) for KT(t+1)
        if (t + 1 < NT) {
#pragma unroll
            for (int j = 0; j < 2; ++j) {
                bN01[j][0] = *(const f16x8*)(lbn + bOff + j * 8192 + gk0);
                bN01[j][1] = *(const f16x8*)(lbn + bOff + j * 8192 + gk1);
            }
        }
        __builtin_amdgcn_s_setprio(1);
#pragma unroll
        for (int k = 0; k < 2; ++k)
#pragma unroll
            for (int i = 0; i < 4; ++i)
#pragma unroll
                for (int j = 0; j < 2; ++j)
                    acc[4 + i][2 + j] = __builtin_amdgcn_mfma_f32_16x16x32_f16(
                        aH1[i][k], bN23[j][k], acc[4 + i][2 + j], 0, 0, 0);
        __builtin_amdgcn_s_setprio(0);
    }

    // Epilogue (verified): C/D col = lane&15, row = (lane>>4)*4 + reg.
#pragma unroll
    for (int j = 0; j < 4; ++j) {
        const int col = colBase + (j * 4 + wn) * 16 + l15;
        const float bj = bias[col];
#pragma unroll
        for (int r = 0; r < 8; ++r) {
            const size_t rb = (size_t)(rowBase + (r * 2 + wm) * 16 + lq * 4) * NN + col;
#pragma unroll
            for (int v = 0; v < 4; ++v)
                out[rb + (size_t)v * NN] = fast_tanh(acc[r][j][v] + bj);
        }
    }
}

// ---------------------------------------------------------------------------
// Fallback (only if workspace too small): naive fp32 tiled GEMM.
__global__ void naive_gemm_kernel(const float* __restrict__ x,
                                  const float* __restrict__ W,
                                  const float* __restrict__ b,
                                  float* __restrict__ out) {
    __shared__ float xs[16][17], ws[16][17];
    int n = blockIdx.x * 16 + threadIdx.x;
    int m = blockIdx.y * 16 + threadIdx.y;
    float s = 0.f;
    for (int k0 = 0; k0 < DIM; k0 += 16) {
        xs[threadIdx.y][threadIdx.x] = x[(size_t)m * DIM + k0 + threadIdx.x];
        ws[threadIdx.y][threadIdx.x] =
            W[(size_t)(blockIdx.x * 16 + threadIdx.y) * DIM + k0 + threadIdx.x];
        __syncthreads();
#pragma unroll
        for (int kk = 0; kk < 16; kk++) s += xs[threadIdx.y][kk] * ws[threadIdx.x][kk];
        __syncthreads();
    }
    out[(size_t)m * NN + n] = tanhf(s + b[n]);
}

// ---------------------------------------------------------------------------
extern "C" void kernel_launch(void* const* d_in, const int* in_sizes, int n_in,
                              void* d_out, int out_size, void* d_ws, size_t ws_size,
                              hipStream_t stream) {
    const float* x = (const float*)d_in[0];
    const float* W = (const float*)d_in[1];
    const float* b = (const float*)d_in[2];
    float* out = (float*)d_out;

    const size_t need = A_BYTES + B_BYTES;   // 25.2 MB
    if (ws_size < need) {
        dim3 grid(NN / 16, SEQ / 16), block(16, 16);
        naive_gemm_kernel<<<grid, block, 0, stream>>>(x, W, b, out);
        return;
    }

    _Float16* Abuf = (_Float16*)d_ws;
    _Float16* Bbuf = Abuf + (size_t)SEQ * DIM;

    convert_kernel<<<12288, 256, 0, stream>>>(x, W, (f16x4*)Abuf, (f16x4*)Bbuf);

    gemm_tanh_kernel<<<512, 512, 0, stream>>>(Abuf, Bbuf, b, out);
}